// Round 13
// baseline (14.208 us; speedup 1.0000x reference)
//
#include <hip/hip_runtime.h>

// SDF Chamfer loss, H=W=64, 2 images. TWO kernels, 2-slot LDS cell tables.
//
// Cell table: 4096 cells x 2 slots x float2 = 64 KiB per block.
//   slot0 <- vertical edges, slot1 <- horizontal edges, at cell floor(point).
//   2 slots are exact for all inputs: a frac==1 point requires v2==0, and the
//   adjacent edge (v1==0, frac==0) then produces the IDENTICAL point into the
//   same slot -> all write races carry identical values -> deterministic.
// Query: exact expanding Chebyshev-ring search; after scanning rings <= r,
//   any unscanned point is at distance >= r, so stop when best^2 <= r^2.
//
// work_kernel: 128 blocks = imgset(4) x sub(32), 1024 threads. Each block
//   builds the OPPOSITE set's table in its own LDS, answers 252 queries,
//   plus a 64-px L1 slice. final_kernel combines.
// ws float layout: [0..127]   chamfer partial sums (per block)
//                  [128..255] query-mask counts    (per block)
//                  [256..383] L1 partial sums      (per block; img = blk>>6)
#define HH 64
#define WW 64
#define NV ((HH-1)*WW)        // 4032
#define NP (NV + HH*(WW-1))   // 8064
#define QPB 252               // queries per block (32 subs x 252 = 8064)
#define EPSF 1e-8f
#define BIGF 3.0e38f
#define SENTC 1e9f

// point (R,C), mask m, and 2-slot cell index: cslot = cell*2 + axis.
__device__ __forceinline__ void edge_eval(const float* __restrict__ sdf, int e,
                                          float& R, float& C, bool& m, int& cslot) {
    float v1, v2;
    if (e < NV) {                       // vertical: rows i, i+1
        int i = e >> 6, j = e & 63;
        v1 = sdf[i * WW + j];
        v2 = sdf[i * WW + WW + j];
        float a = fabsf(v1) / (fabsf(v1) + fabsf(v2) + EPSF);
        float frac = (v1 == 0.f) ? 0.f : ((v2 == 0.f) ? 1.f : a);
        R = (float)i + frac; C = (float)j;
        cslot = ((((int)R) << 6) + j) << 1;           // floor(R): i or i+1
    } else {                            // horizontal: cols j, j+1
        int eh = e - NV;
        int i = eh / (WW - 1), j = eh % (WW - 1);
        v1 = sdf[i * WW + j];
        v2 = sdf[i * WW + j + 1];
        float a = fabsf(v1) / (fabsf(v1) + fabsf(v2) + EPSF);
        float frac = (v1 == 0.f) ? 0.f : ((v2 == 0.f) ? 1.f : a);
        R = (float)i; C = (float)j + frac;
        cslot = (((i << 6) + (int)C) << 1) | 1;       // floor(C): j or j+1
    }
    m = (v1 == 0.f) || (v2 == 0.f) || (v1 * v2 < 0.f);
}

__device__ __forceinline__ void scan_cell(const float2* __restrict__ cells, int cell,
                                          float qx, float qy, float& best) {
    float4 a = ((const float4*)cells)[cell];          // both slots in one read
    float dx0 = qx - a.x, dy0 = qy - a.y, dx1 = qx - a.z, dy1 = qy - a.w;
    float d0 = __builtin_fmaf(dx0, dx0, dy0 * dy0);
    float d1 = __builtin_fmaf(dx1, dx1, dy1 * dy1);
    best = fminf(best, fminf(d0, d1));
}

__global__ __launch_bounds__(1024) void work_kernel(const float* __restrict__ pred,
                                                    const float* __restrict__ gt,
                                                    float* __restrict__ ws) {
    int blk = blockIdx.x;               // 128 blocks
    int imgset = blk >> 5, sub = blk & 31;
    int b = imgset >> 1, set = imgset & 1;
    int opp = imgset ^ 1;
    const float* qsdf = (set ? gt : pred) + b * (HH * WW);
    const float* csdf = ((opp & 1) ? gt : pred) + (opp >> 1) * (HH * WW);
    int tid = threadIdx.x, lane = tid & 63, wid = tid >> 6;

    __shared__ __align__(16) float2 cells[4096 * 2];  // 64 KiB table
    __shared__ float redA[16], redB[16], redC[16];

    // sentinel init: 4096 float4, 4 per thread
    float4* c4 = (float4*)cells;
    #pragma unroll
    for (int k = 0; k < 4; ++k)
        c4[tid + k * 1024] = make_float4(SENTC, SENTC, SENTC, SENTC);
    __syncthreads();

    // build opposite table: all write races carry identical values
    #pragma unroll
    for (int k = 0; k < 8; ++k) {
        int e = tid + k * 1024;
        if (e < NP) {
            float R, C; bool m; int cslot;
            edge_eval(csdf, e, R, C, m, cslot);
            if (m) cells[cslot] = make_float2(R, C);
        }
    }
    __syncthreads();

    // query own 252-edge slice: 1 query per thread
    float acc = 0.f, mycnt = 0.f;
    if (tid < QPB) {
        int e = sub * QPB + tid;
        float R, C; bool m; int cs;
        edge_eval(qsdf, e, R, C, m, cs);
        if (m) {
            mycnt = 1.f;
            float best = BIGF;
            int ci = (int)R, cj = (int)C;
            // rings 0-1: 9 cells, 9 independent float4 loads
            #pragma unroll
            for (int di = -1; di <= 1; ++di) {
                #pragma unroll
                for (int dj = -1; dj <= 1; ++dj) {
                    int i = ci + di, j = cj + dj;
                    if ((unsigned)i < 64u && (unsigned)j < 64u)
                        scan_cell(cells, (i << 6) + j, R, C, best);
                }
            }
            // rings >= 2 (rare)
            for (int r = 2; r < 64 && best > (float)((r - 1) * (r - 1)); ++r) {
                int ilo = max(ci - r, 0), ihi = min(ci + r, 63);
                int jlo = max(cj - r, 0), jhi = min(cj + r, 63);
                for (int i = ilo; i <= ihi; ++i) {
                    if (i == ci - r || i == ci + r) {
                        for (int j = jlo; j <= jhi; ++j)
                            scan_cell(cells, (i << 6) + j, R, C, best);
                    } else {
                        if (cj - r >= 0) scan_cell(cells, (i << 6) + (cj - r), R, C, best);
                        if (cj + r <= 63) scan_cell(cells, (i << 6) + (cj + r), R, C, best);
                    }
                }
            }
            acc = sqrtf(best);
        }
    }

    // L1 slice: 16 float4 per block over flat [2048] float4 (2 images)
    float l1 = 0.f;
    if (tid < 16) {
        const float4* p4 = (const float4*)pred;
        const float4* g4 = (const float4*)gt;
        int idx = blk * 16 + tid;
        float4 a = p4[idx], bb = g4[idx];
        l1 = fabsf(a.x - bb.x) + fabsf(a.y - bb.y) + fabsf(a.z - bb.z) + fabsf(a.w - bb.w);
    }

    // block reduce (16 waves)
    for (int o = 32; o; o >>= 1) {
        acc   += __shfl_down(acc, o, 64);
        mycnt += __shfl_down(mycnt, o, 64);
        l1    += __shfl_down(l1, o, 64);
    }
    if (lane == 0) { redA[wid] = acc; redB[wid] = mycnt; redC[wid] = l1; }
    __syncthreads();
    if (tid == 0) {
        float sA = 0.f, sB = 0.f, sC = 0.f;
        #pragma unroll
        for (int w = 0; w < 16; ++w) { sA += redA[w]; sB += redB[w]; sC += redC[w]; }
        ws[blk] = sA;
        ws[128 + blk] = sB;
        ws[256 + blk] = sC;
    }
}

// 1 block, 256 threads: combine 128 sums/counts/L1 partials -> loss.
__global__ __launch_bounds__(256) void final_kernel(const float* __restrict__ ws,
                                                    float* __restrict__ out) {
    int tid = threadIdx.x, lane = tid & 63, wid = tid >> 6;
    __shared__ float sums[4], cnts[4], l1s[2];

    // wave w owns imgset w: 32 partials each
    float v = (lane < 32) ? ws[wid * 32 + lane] : 0.f;
    float c = (lane < 32) ? ws[128 + wid * 32 + lane] : 0.f;
    for (int o = 16; o; o >>= 1) { v += __shfl_down(v, o, 32); c += __shfl_down(c, o, 32); }
    if (lane == 0) { sums[wid] = v; cnts[wid] = c; }

    // L1: waves 0,1 own images 0,1: 64 partials each (img = blk>>6)
    float l = (wid < 2) ? ws[256 + wid * 64 + lane] : 0.f;
    for (int o = 32; o; o >>= 1) l += __shfl_down(l, o, 64);
    if (wid < 2 && lane == 0) l1s[wid] = l;
    __syncthreads();

    if (tid == 0) {
        float loss = 0.f;
        for (int b = 0; b < 2; ++b) {
            float mean1 = sums[2 * b + 0] / fmaxf(cnts[2 * b + 0], 1.f);  // pred->gt
            float mean2 = sums[2 * b + 1] / fmaxf(cnts[2 * b + 1], 1.f);  // gt->pred
            loss += l1s[b] * (1.f / (HH * WW)) + fabsf(-mean1 + mean2);
        }
        out[0] = loss * 0.5f;
    }
}

extern "C" void kernel_launch(void* const* d_in, const int* in_sizes, int n_in,
                              void* d_out, int out_size, void* d_ws, size_t ws_size,
                              hipStream_t stream) {
    const float* pred = (const float*)d_in[0];
    const float* gt   = (const float*)d_in[1];
    float* ws  = (float*)d_ws;
    float* out = (float*)d_out;

    hipLaunchKernelGGL(work_kernel,  dim3(128), dim3(1024), 0, stream, pred, gt, ws);
    hipLaunchKernelGGL(final_kernel, dim3(1),   dim3(256),  0, stream, ws, out);
}